// Round 12
// baseline (152.618 us; speedup 1.0000x reference)
//
#include <hip/hip_runtime.h>
#include <hip/hip_bf16.h>

// Problem constants
#define SEQ   4096
#define DM    1024
#define NH    16
#define HD    64
#define N3    3072       // 3*DM
#define WIN   512

#define LOG2E 1.4426950408889634f

typedef __attribute__((ext_vector_type(8))) short short8;   // 8 bf16 (4 VGPRs)
typedef __attribute__((ext_vector_type(4))) short short4v;  // 8B half-frag
typedef __attribute__((ext_vector_type(4))) float float4v;  // 4 fp32 acc

__device__ __forceinline__ float bf16_bits_to_float(unsigned short u) {
  return __uint_as_float(((unsigned int)u) << 16);
}

// async 16B global->LDS (m97 path: emits global_load_lds_dwordx4)
typedef __attribute__((address_space(3))) void lds_void_t;
typedef __attribute__((address_space(1))) const void gbl_void_t;
__device__ __forceinline__ void async_copy16(void* lds_dst, const void* g_src) {
  __builtin_amdgcn_global_load_lds((gbl_void_t*)g_src, (lds_void_t*)lds_dst,
                                   16, 0, 0);
}

// ---------------------------------------------------------------------------
// Block-level dtype detection (LDS reduction): 1 = fp32 inputs, 0 = bf16.
// ---------------------------------------------------------------------------
template <int NT>
__device__ __forceinline__ int detect_fp32(const unsigned short* __restrict__ probe,
                                           float* red) {
  const int t = threadIdx.x;
  float mx = 0.0f;
#pragma unroll
  for (int p = 0; p < 8; ++p) {
    float v = bf16_bits_to_float(probe[(t * 8 + p) * 2]);
    if (v != v) v = 1e38f;
    mx = fmaxf(mx, fabsf(v));
  }
  red[t] = mx;
  __syncthreads();
  for (int s = NT / 2; s > 0; s >>= 1) {
    if (t < s) red[t] = fmaxf(red[t], red[t + s]);
    __syncthreads();
  }
  const int fl = red[0] > 100.0f ? 1 : 0;
  __syncthreads();
  return fl;
}

// Wave-level dtype detection (no LDS, no barriers).
__device__ __forceinline__ int detect_fp32_wave(
    const unsigned short* __restrict__ probe) {
  const int lane = threadIdx.x & 63;
  float mx = 0.0f;
#pragma unroll
  for (int p = 0; p < 8; ++p) {
    float v = bf16_bits_to_float(probe[(lane * 8 + p) * 2]);
    if (v != v) v = 1e38f;
    mx = fmaxf(mx, fabsf(v));
  }
  return __any(mx > 100.0f) ? 1 : 0;
}

// ---------------------------------------------------------------------------
// Kernel 1 (merged prep): blocks [0,2048) convert X -> xb bf16;
// blocks [2048, 2816) transpose/convert W -> WT bf16.
// ---------------------------------------------------------------------------
__global__ __launch_bounds__(256) void prep(
    const void* __restrict__ x, const void* __restrict__ w,
    __hip_bfloat16* __restrict__ xb, __hip_bfloat16* __restrict__ wt) {
  __shared__ __hip_bfloat16 tile[64][66];
  __shared__ float red[256];
  const int t = threadIdx.x;
  if (blockIdx.x < 2048) {
    const int fl = detect_fp32<256>((const unsigned short*)x, red);
    const int i0 = (blockIdx.x * 256 + t) * 8;
    if (fl) {
      const float* xf = (const float*)x + i0;
      float4 f0 = *(const float4*)(xf);
      float4 f1 = *(const float4*)(xf + 4);
      __hip_bfloat16 tmp[8];
      tmp[0] = __float2bfloat16(f0.x); tmp[1] = __float2bfloat16(f0.y);
      tmp[2] = __float2bfloat16(f0.z); tmp[3] = __float2bfloat16(f0.w);
      tmp[4] = __float2bfloat16(f1.x); tmp[5] = __float2bfloat16(f1.y);
      tmp[6] = __float2bfloat16(f1.z); tmp[7] = __float2bfloat16(f1.w);
      *(uint4*)&xb[i0] = *(const uint4*)tmp;
    } else {
      *(uint4*)&xb[i0] = *(const uint4*)((const __hip_bfloat16*)x + i0);
    }
  } else {
    const int bid = blockIdx.x - 2048;
    const int fl = detect_fp32<256>((const unsigned short*)w, red);
    const int n0 = (bid % 48) * 64;
    const int k0 = (bid / 48) * 64;
    const int tx = t & 63, ty0 = t >> 6;
    if (fl) {
      const float* wf = (const float*)w;
#pragma unroll
      for (int p = 0; p < 16; ++p) {
        int row = ty0 + p * 4;
        tile[row][tx] = __float2bfloat16(wf[(k0 + row) * N3 + n0 + tx]);
      }
    } else {
      const __hip_bfloat16* wb = (const __hip_bfloat16*)w;
#pragma unroll
      for (int p = 0; p < 16; ++p) {
        int row = ty0 + p * 4;
        tile[row][tx] = wb[(k0 + row) * N3 + n0 + tx];
      }
    }
    __syncthreads();
#pragma unroll
    for (int r = 0; r < 2; ++r) {
      int oe = r * 2048 + t * 8;
      int nr = oe >> 6, kc = oe & 63;
      __hip_bfloat16 v[8];
#pragma unroll
      for (int e = 0; e < 8; ++e) v[e] = tile[kc + e][nr];
      *(uint4*)&wt[(n0 + nr) * DM + k0 + kc] = *(const uint4*)v;
    }
  }
}

// ---------------------------------------------------------------------------
// Kernel 2: KQV = xb[4096,1024] * W -> bf16 [4096,3072]. BK=64 via two
// ping-pong 128x32 buffer pairs (unchanged — near the m97 plateau).
// ---------------------------------------------------------------------------
__global__ __launch_bounds__(256) void gemm_kqv(
    const __hip_bfloat16* __restrict__ A,    // xb [4096][1024]
    const __hip_bfloat16* __restrict__ BT,   // WT [3072][1024]
    __hip_bfloat16* __restrict__ C) {        // kqv [4096][3072]
  __shared__ __align__(16) __hip_bfloat16 As[2][128 * 32];
  __shared__ __align__(16) __hip_bfloat16 Bs[2][128 * 32];
  const int m0 = blockIdx.y * 128;
  const int n0 = blockIdx.x * 128;
  const int t = threadIdx.x;
  const int wave = t >> 6, lane = t & 63;
  const int wm = wave >> 1, wn = wave & 1;
  const int l15 = lane & 15, quad = lane >> 4;

  const int srow0 = wave * 16 + (lane >> 2);
  const int scol  = (lane & 3) * 8;
  const int sbyte = wave * 1024 + lane * 16;

  float4v acc[4][4] = {};

  for (int k0 = 0; k0 < DM; k0 += 64) {
    __syncthreads();
#pragma unroll
    for (int half = 0; half < 2; ++half) {
      const int kk = k0 + half * 32;
#pragma unroll
      for (int r = 0; r < 2; ++r) {
        const int row = srow0 + r * 64;
        async_copy16((char*)As[half] + r * 4096 + sbyte,
                     &A[(m0 + row) * DM + kk + scol]);
        async_copy16((char*)Bs[half] + r * 4096 + sbyte,
                     &BT[(n0 + row) * DM + kk + scol]);
      }
    }
    __syncthreads();

#pragma unroll
    for (int half = 0; half < 2; ++half) {
      short8 a[4], b[4];
#pragma unroll
      for (int mi = 0; mi < 4; ++mi)
        a[mi] = *(const short8*)(&As[half][(wm * 64 + mi * 16 + l15) * 32 + quad * 8]);
#pragma unroll
      for (int ni = 0; ni < 4; ++ni)
        b[ni] = *(const short8*)(&Bs[half][(wn * 64 + ni * 16 + l15) * 32 + quad * 8]);
#pragma unroll
      for (int mi = 0; mi < 4; ++mi)
#pragma unroll
        for (int ni = 0; ni < 4; ++ni)
          acc[mi][ni] = __builtin_amdgcn_mfma_f32_16x16x32_bf16(
              a[mi], b[ni], acc[mi][ni], 0, 0, 0);
    }
  }

#pragma unroll
  for (int mi = 0; mi < 4; ++mi)
#pragma unroll
    for (int ni = 0; ni < 4; ++ni)
#pragma unroll
      for (int r = 0; r < 4; ++r) {
        int row = m0 + wm * 64 + mi * 16 + quad * 4 + r;
        int col = n0 + wn * 64 + ni * 16 + l15;
        C[row * N3 + col] = __float2bfloat16(acc[mi][ni][r]);
      }
}

// ---------------------------------------------------------------------------
// Kernel 3: MFMA flash attention, fixed-max softmax (m=0).
// ROUND 12: ONE barrier per K-block iteration via LDS double-buffer with a
// SINGLE register staging set (round 10's spill came from TWO conditional
// reg sets; one set = 16 VGPRs, no spill). Invariant entering iter b:
// buf[b&1] holds tile b (ds_written a full iteration ago -> MFMAs start with
// zero lgkmcnt stall), regs hold tile b+1. Body: ds_write regs->buf[1-cur]
// (reads regs at issue), prefetch tile b+2 -> regs (in-order WAR safe),
// compute from buf[cur], single __syncthreads. At the barrier the prefetch
// has had the whole compute phase to land (kqv is L2-resident) -> ~no drain.
// l via MFMA ones-block (dt=4). Ps wave-private, no barrier.
// LDS: 2*Ks 18.4K + 2*Vt 17.0K + Ones 2.2K + Ps 9.2K = 46.1K -> 3 blocks/CU.
// ---------------------------------------------------------------------------
#define KS_STRIDE 72
#define VT_STRIDE 68
#define KS_SZ (64 * KS_STRIDE)
#define VT_SZ (64 * VT_STRIDE)

__global__ __launch_bounds__(256, 3) void attn(
    const __hip_bfloat16* __restrict__ kqv,
    const unsigned short* __restrict__ xprobe,   // d_in[0], dtype probe only
    void* __restrict__ out) {
  __shared__ __align__(16) __hip_bfloat16 Ks[2 * KS_SZ];        // [buf][k][d]
  __shared__ __align__(16) __hip_bfloat16 Vt[2 * VT_SZ];        // [buf][d][key]
  __shared__ __align__(16) __hip_bfloat16 Ones[16 * VT_STRIDE]; // row0=1, rest 0
  __shared__ __align__(16) __hip_bfloat16 Ps[64 * KS_STRIDE];   // [q][key]

  const int fl = detect_fp32_wave(xprobe);     // no barriers, no LDS
  const int h  = blockIdx.y;
  const int bx = blockIdx.x;
  // XCD swizzle: blocks with equal bx%8 get 8 consecutive tiles -> shared
  // K/V windows in one XCD's L2.
  const int i0 = 64 * ((bx & 7) * 8 + (bx >> 3));
  const int t    = threadIdx.x;
  const int wave = t >> 6, lane = t & 63;
  const int l15 = lane & 15, quad = lane >> 4;
  const float slope2  = exp2f(-0.5f * (float)(h + 1)) * LOG2E;  // m_h*log2(e)
  const float nslope2 = -slope2;                                // bias = nslope2*(i-j)
  const float qscale  = LOG2E / 32.0f;

  // Ones block (row 0 = 1.0, rows 1..15 = 0) — written once, pre-barrier
  for (int idx = t; idx < 16 * VT_STRIDE; idx += 256) {
    int rr = idx / VT_STRIDE;
    ((unsigned short*)Ones)[idx] = (rr == 0) ? 0x3F80 : 0;
  }

  // Q fragments direct to registers: A[m=l15][k=quad*8+j], rows wave*16+l15
  short8 aq[2];
#pragma unroll
  for (int ks2 = 0; ks2 < 2; ++ks2)
    aq[ks2] = *(const short8*)&kqv[(i0 + wave * 16 + l15) * N3 + DM + h * HD +
                                   ks2 * 32 + quad * 8];

  float4v o[5] = {};   // o[dt][r]: row quad*4+r, col dt*16+l15; dt=4 is l-column

  const int jlo  = max(0, i0 - WIN);       // 64-aligned
  const int nblk = (i0 + 64 - jlo) >> 6;   // <= 9

  // staging geometry (single register set: 4 x uint4 = 16 VGPRs)
  const int krow0 = t >> 3, krow1 = (t >> 3) + 32, kd0 = (t & 7) * 8;
  const int vr0 = (t >> 3) * 2, vd0 = (t & 7) * 8;
  uint4 kregA, kregB, vregA, vregB;

  // ---- prologue: tile 0 -> buf 0; tile 1 -> regs ----
  kregA = *(const uint4*)&kqv[(jlo + krow0) * N3 + h * HD + kd0];
  kregB = *(const uint4*)&kqv[(jlo + krow1) * N3 + h * HD + kd0];
  vregA = *(const uint4*)&kqv[(jlo + vr0) * N3 + 2 * DM + h * HD + vd0];
  vregB = *(const uint4*)&kqv[(jlo + vr0 + 1) * N3 + 2 * DM + h * HD + vd0];
  *(uint4*)&Ks[krow0 * KS_STRIDE + kd0] = kregA;
  *(uint4*)&Ks[krow1 * KS_STRIDE + kd0] = kregB;
  {
    const unsigned short* pa = (const unsigned short*)&vregA;
    const unsigned short* pb = (const unsigned short*)&vregB;
#pragma unroll
    for (int e = 0; e < 8; ++e) {
      unsigned int pack = (unsigned int)pa[e] | ((unsigned int)pb[e] << 16);
      *(unsigned int*)&Vt[(vd0 + e) * VT_STRIDE + vr0] = pack;
    }
  }
  if (nblk > 1) {
    const int j1 = jlo + 64;
    kregA = *(const uint4*)&kqv[(j1 + krow0) * N3 + h * HD + kd0];
    kregB = *(const uint4*)&kqv[(j1 + krow1) * N3 + h * HD + kd0];
    vregA = *(const uint4*)&kqv[(j1 + vr0) * N3 + 2 * DM + h * HD + vd0];
    vregB = *(const uint4*)&kqv[(j1 + vr0 + 1) * N3 + 2 * DM + h * HD + vd0];
  }
  __syncthreads();

#define ATTN_STEP(B, CUR)                                                      \
  {                                                                            \
    const int j0 = jlo + (B) * 64;                                             \
    /* stage tile B+1 (regs) into buf 1-CUR; readers finished at last barrier */\
    if ((B) + 1 < nblk) {                                                      \
      __hip_bfloat16* KsN = Ks + (1 - (CUR)) * KS_SZ;                          \
      __hip_bfloat16* VtN = Vt + (1 - (CUR)) * VT_SZ;                          \
      *(uint4*)&KsN[krow0 * KS_STRIDE + kd0] = kregA;                          \
      *(uint4*)&KsN[krow1 * KS_STRIDE + kd0] = kregB;                          \
      const unsigned short* pa = (const unsigned short*)&vregA;                \
      const unsigned short* pb = (const unsigned short*)&vregB;                \
      _Pragma("unroll")                                                        \
      for (int e = 0; e < 8; ++e) {                                            \
        unsigned int pack = (unsigned int)pa[e] | ((unsigned int)pb[e] << 16); \
        *(unsigned int*)&VtN[(vd0 + e) * VT_STRIDE + vr0] = pack;              \
      }                                                                        \
    }                                                                          \
    /* prefetch tile B+2 into regs (WAR on ds_write sources is in-order ok) */ \
    if ((B) + 2 < nblk) {                                                      \
      const int jn = jlo + ((B) + 2) * 64;                                     \
      kregA = *(const uint4*)&kqv[(jn + krow0) * N3 + h * HD + kd0];           \
      kregB = *(const uint4*)&kqv[(jn + krow1) * N3 + h * HD + kd0];           \
      vregA = *(const uint4*)&kqv[(jn + vr0) * N3 + 2 * DM + h * HD + vd0];    \
      vregB = *(const uint4*)&kqv[(jn + vr0 + 1) * N3 + 2 * DM + h * HD + vd0];\
    }                                                                          \
    const __hip_bfloat16* KsC = Ks + (CUR) * KS_SZ;                            \
    const __hip_bfloat16* VtC = Vt + (CUR) * VT_SZ;                            \
    /* S = Q*K^T (buf CUR was filled a full iteration ago: no lgkm stall) */   \
    float4v sacc[4] = {};                                                      \
    _Pragma("unroll")                                                          \
    for (int ks2 = 0; ks2 < 2; ++ks2) {                                        \
      _Pragma("unroll")                                                        \
      for (int nt = 0; nt < 4; ++nt) {                                         \
        short8 bk = *(const short8*)&KsC[(nt * 16 + l15) * KS_STRIDE +         \
                                         ks2 * 32 + quad * 8];                 \
        sacc[nt] = __builtin_amdgcn_mfma_f32_16x16x32_bf16(aq[ks2], bk,        \
                                                           sacc[nt], 0, 0, 0); \
      }                                                                        \
    }                                                                          \
    /* fixed-max softmax: p = exp2(x), masked -> 0 */                          \
    const int dbase = (i0 + wave * 16 + quad * 4) - (j0 + l15);                \
    const float s16 = nslope2 * -16.0f;                                        \
    _Pragma("unroll")                                                          \
    for (int r = 0; r < 4; ++r) {                                              \
      float bias = nslope2 * (float)(dbase + r);                               \
      int rel = dbase + r;                                                     \
      _Pragma("unroll")                                                        \
      for (int nt = 0; nt < 4; ++nt) {                                         \
        float x = fmaf(sacc[nt][r], qscale, bias);                             \
        x = ((unsigned)rel <= (unsigned)WIN) ? x : -200.0f;                    \
        Ps[(wave * 16 + quad * 4 + r) * KS_STRIDE + nt * 16 + l15] =           \
            __float2bfloat16(exp2f(x));                                        \
        bias += s16;                                                           \
        rel -= 16;                                                             \
      }                                                                        \
    }                                                                          \
    /* O += P*V (dt 0..3) ; l += P*1 (dt 4: Ones block) */                     \
    _Pragma("unroll")                                                          \
    for (int ks = 0; ks < 64; ks += 32) {                                      \
      short8 ap = *(const short8*)&Ps[(wave * 16 + l15) * KS_STRIDE + ks +     \
                                      quad * 8];                               \
      _Pragma("unroll")                                                        \
      for (int dt = 0; dt < 5; ++dt) {                                         \
        const __hip_bfloat16* vp =                                             \
            (dt < 4) ? &VtC[(dt * 16 + l15) * VT_STRIDE + ks + quad * 8]       \
                     : &Ones[l15 * VT_STRIDE + ks + quad * 8];                 \
        short4v v0 = *(const short4v*)vp;                                      \
        short4v v1 = *(const short4v*)(vp + 4);                                \
        short8 bv = __builtin_shufflevector(v0, v1, 0, 1, 2, 3, 4, 5, 6, 7);   \
        o[dt] = __builtin_amdgcn_mfma_f32_16x16x32_bf16(ap, bv, o[dt], 0, 0, 0); \
      }                                                                        \
    }                                                                          \
    __syncthreads();  /* the ONLY barrier: prefetch had whole compute to land */\
  }

  for (int b = 0; b < nblk; b += 2) {
    ATTN_STEP(b, 0);
    if (b + 1 < nblk) ATTN_STEP(b + 1, 1);
  }
#undef ATTN_STEP

  // ---- epilogue: l lives in o[4] col 0 (lane l15==0 of each quad group) ----
#pragma unroll
  for (int r = 0; r < 4; ++r) {
    const float l = __shfl(o[4][r], quad * 16, 64);   // broadcast from l15==0 lane
    const float inv_l = 1.0f / l;    // l >= 2^-2: diagonal key j=i always valid
    const int row = i0 + wave * 16 + quad * 4 + r;
#pragma unroll
    for (int dt = 0; dt < 4; ++dt) {
      const int idx = row * DM + h * HD + dt * 16 + l15;
      const float v = o[dt][r] * inv_l;
      if (fl) ((float*)out)[idx] = v;
      else    ((__hip_bfloat16*)out)[idx] = __float2bfloat16(v);
    }
  }
}

// ---------------------------------------------------------------------------
extern "C" void kernel_launch(void* const* d_in, const int* in_sizes, int n_in,
                              void* d_out, int out_size, void* d_ws, size_t ws_size,
                              hipStream_t stream) {
  char* ws = (char*)d_ws;
  __hip_bfloat16* wt  = (__hip_bfloat16*)(ws + 4096);          // 6 MB
  __hip_bfloat16* kqv = (__hip_bfloat16*)(ws + 4096 + 6291456);// 24 MB
  // xb lives in d_out's first 8 MB: dead until attn's epilogue overwrites all
  // of d_out, and gemm_kqv (the only xb reader) completes before attn runs.
  __hip_bfloat16* xb  = (__hip_bfloat16*)d_out;

  hipLaunchKernelGGL(prep, dim3(2048 + 768), dim3(256), 0, stream,
                     d_in[0], d_in[1], xb, wt);
  hipLaunchKernelGGL(gemm_kqv, dim3(24, 32), dim3(256), 0, stream, xb, wt, kqv);
  hipLaunchKernelGGL(attn, dim3(64, 16), dim3(256), 0, stream,
                     kqv, (const unsigned short*)d_in[0], d_out);
}

// Round 13
// 147.931 us; speedup vs baseline: 1.0317x; 1.0317x over previous
//
#include <hip/hip_runtime.h>
#include <hip/hip_bf16.h>

// Problem constants
#define SEQ   4096
#define DM    1024
#define NH    16
#define HD    64
#define N3    3072       // 3*DM
#define WIN   512

#define LOG2E 1.4426950408889634f

typedef __attribute__((ext_vector_type(8))) short short8;   // 8 bf16 (4 VGPRs)
typedef __attribute__((ext_vector_type(4))) short short4v;  // 8B half-frag
typedef __attribute__((ext_vector_type(4))) float float4v;  // 4 fp32 acc

__device__ __forceinline__ float bf16_bits_to_float(unsigned short u) {
  return __uint_as_float(((unsigned int)u) << 16);
}

// async 16B global->LDS (m97 path: emits global_load_lds_dwordx4)
typedef __attribute__((address_space(3))) void lds_void_t;
typedef __attribute__((address_space(1))) const void gbl_void_t;
__device__ __forceinline__ void async_copy16(void* lds_dst, const void* g_src) {
  __builtin_amdgcn_global_load_lds((gbl_void_t*)g_src, (lds_void_t*)lds_dst,
                                   16, 0, 0);
}

// ---------------------------------------------------------------------------
// Block-level dtype detection (LDS reduction): 1 = fp32 inputs, 0 = bf16.
// ---------------------------------------------------------------------------
template <int NT>
__device__ __forceinline__ int detect_fp32(const unsigned short* __restrict__ probe,
                                           float* red) {
  const int t = threadIdx.x;
  float mx = 0.0f;
#pragma unroll
  for (int p = 0; p < 8; ++p) {
    float v = bf16_bits_to_float(probe[(t * 8 + p) * 2]);
    if (v != v) v = 1e38f;
    mx = fmaxf(mx, fabsf(v));
  }
  red[t] = mx;
  __syncthreads();
  for (int s = NT / 2; s > 0; s >>= 1) {
    if (t < s) red[t] = fmaxf(red[t], red[t + s]);
    __syncthreads();
  }
  const int fl = red[0] > 100.0f ? 1 : 0;
  __syncthreads();
  return fl;
}

// Wave-level dtype detection (no LDS, no barriers).
__device__ __forceinline__ int detect_fp32_wave(
    const unsigned short* __restrict__ probe) {
  const int lane = threadIdx.x & 63;
  float mx = 0.0f;
#pragma unroll
  for (int p = 0; p < 8; ++p) {
    float v = bf16_bits_to_float(probe[(lane * 8 + p) * 2]);
    if (v != v) v = 1e38f;
    mx = fmaxf(mx, fabsf(v));
  }
  return __any(mx > 100.0f) ? 1 : 0;
}

// ---------------------------------------------------------------------------
// Kernel 1 (merged prep): blocks [0,2048) convert X -> xb bf16;
// blocks [2048, 2816) transpose/convert W -> WT bf16.
// ---------------------------------------------------------------------------
__global__ __launch_bounds__(256) void prep(
    const void* __restrict__ x, const void* __restrict__ w,
    __hip_bfloat16* __restrict__ xb, __hip_bfloat16* __restrict__ wt) {
  __shared__ __hip_bfloat16 tile[64][66];
  __shared__ float red[256];
  const int t = threadIdx.x;
  if (blockIdx.x < 2048) {
    const int fl = detect_fp32<256>((const unsigned short*)x, red);
    const int i0 = (blockIdx.x * 256 + t) * 8;
    if (fl) {
      const float* xf = (const float*)x + i0;
      float4 f0 = *(const float4*)(xf);
      float4 f1 = *(const float4*)(xf + 4);
      __hip_bfloat16 tmp[8];
      tmp[0] = __float2bfloat16(f0.x); tmp[1] = __float2bfloat16(f0.y);
      tmp[2] = __float2bfloat16(f0.z); tmp[3] = __float2bfloat16(f0.w);
      tmp[4] = __float2bfloat16(f1.x); tmp[5] = __float2bfloat16(f1.y);
      tmp[6] = __float2bfloat16(f1.z); tmp[7] = __float2bfloat16(f1.w);
      *(uint4*)&xb[i0] = *(const uint4*)tmp;
    } else {
      *(uint4*)&xb[i0] = *(const uint4*)((const __hip_bfloat16*)x + i0);
    }
  } else {
    const int bid = blockIdx.x - 2048;
    const int fl = detect_fp32<256>((const unsigned short*)w, red);
    const int n0 = (bid % 48) * 64;
    const int k0 = (bid / 48) * 64;
    const int tx = t & 63, ty0 = t >> 6;
    if (fl) {
      const float* wf = (const float*)w;
#pragma unroll
      for (int p = 0; p < 16; ++p) {
        int row = ty0 + p * 4;
        tile[row][tx] = __float2bfloat16(wf[(k0 + row) * N3 + n0 + tx]);
      }
    } else {
      const __hip_bfloat16* wb = (const __hip_bfloat16*)w;
#pragma unroll
      for (int p = 0; p < 16; ++p) {
        int row = ty0 + p * 4;
        tile[row][tx] = wb[(k0 + row) * N3 + n0 + tx];
      }
    }
    __syncthreads();
#pragma unroll
    for (int r = 0; r < 2; ++r) {
      int oe = r * 2048 + t * 8;
      int nr = oe >> 6, kc = oe & 63;
      __hip_bfloat16 v[8];
#pragma unroll
      for (int e = 0; e < 8; ++e) v[e] = tile[kc + e][nr];
      *(uint4*)&wt[(n0 + nr) * DM + k0 + kc] = *(const uint4*)v;
    }
  }
}

// ---------------------------------------------------------------------------
// Kernel 2: KQV = xb[4096,1024] * W -> bf16 [4096,3072]. BK=64 via two
// ping-pong 128x32 buffer pairs (near the m97 structural plateau for K=1024).
// ---------------------------------------------------------------------------
__global__ __launch_bounds__(256) void gemm_kqv(
    const __hip_bfloat16* __restrict__ A,    // xb [4096][1024]
    const __hip_bfloat16* __restrict__ BT,   // WT [3072][1024]
    __hip_bfloat16* __restrict__ C) {        // kqv [4096][3072]
  __shared__ __align__(16) __hip_bfloat16 As[2][128 * 32];
  __shared__ __align__(16) __hip_bfloat16 Bs[2][128 * 32];
  const int m0 = blockIdx.y * 128;
  const int n0 = blockIdx.x * 128;
  const int t = threadIdx.x;
  const int wave = t >> 6, lane = t & 63;
  const int wm = wave >> 1, wn = wave & 1;
  const int l15 = lane & 15, quad = lane >> 4;

  const int srow0 = wave * 16 + (lane >> 2);
  const int scol  = (lane & 3) * 8;
  const int sbyte = wave * 1024 + lane * 16;

  float4v acc[4][4] = {};

  for (int k0 = 0; k0 < DM; k0 += 64) {
    __syncthreads();
#pragma unroll
    for (int half = 0; half < 2; ++half) {
      const int kk = k0 + half * 32;
#pragma unroll
      for (int r = 0; r < 2; ++r) {
        const int row = srow0 + r * 64;
        async_copy16((char*)As[half] + r * 4096 + sbyte,
                     &A[(m0 + row) * DM + kk + scol]);
        async_copy16((char*)Bs[half] + r * 4096 + sbyte,
                     &BT[(n0 + row) * DM + kk + scol]);
      }
    }
    __syncthreads();

#pragma unroll
    for (int half = 0; half < 2; ++half) {
      short8 a[4], b[4];
#pragma unroll
      for (int mi = 0; mi < 4; ++mi)
        a[mi] = *(const short8*)(&As[half][(wm * 64 + mi * 16 + l15) * 32 + quad * 8]);
#pragma unroll
      for (int ni = 0; ni < 4; ++ni)
        b[ni] = *(const short8*)(&Bs[half][(wn * 64 + ni * 16 + l15) * 32 + quad * 8]);
#pragma unroll
      for (int mi = 0; mi < 4; ++mi)
#pragma unroll
        for (int ni = 0; ni < 4; ++ni)
          acc[mi][ni] = __builtin_amdgcn_mfma_f32_16x16x32_bf16(
              a[mi], b[ni], acc[mi][ni], 0, 0, 0);
    }
  }

#pragma unroll
  for (int mi = 0; mi < 4; ++mi)
#pragma unroll
    for (int ni = 0; ni < 4; ++ni)
#pragma unroll
      for (int r = 0; r < 4; ++r) {
        int row = m0 + wm * 64 + mi * 16 + quad * 4 + r;
        int col = n0 + wn * 64 + ni * 16 + l15;
        C[row * N3 + col] = __float2bfloat16(acc[mi][ni][r]);
      }
}

// ---------------------------------------------------------------------------
// Kernel 3: MFMA flash attention, fixed-max softmax (m=0).
// ROUND 13 = round-11 revert (best measured config, 148.6 µs total):
// 64-q tiles / 256 thr / single-buffer LDS / 4 blocks/CU; next-tile register
// prefetch issued AFTER the second barrier so nothing is outstanding at any
// __syncthreads. R10 dbuf spilled (WRITE 70MB); R12 single-barrier dbuf was
// neutral-negative (3 blocks/CU). This is the attn latency plateau.
// l via MFMA ones-rows 64..79 of Vt (dt=4). Ps wave-private, no barrier.
// LDS: Ks 9.2K + Vt 10.9K + Ps 9.2K = 29.3 KB -> 4 blocks/CU.
// ---------------------------------------------------------------------------
__global__ __launch_bounds__(256, 4) void attn(
    const __hip_bfloat16* __restrict__ kqv,
    const unsigned short* __restrict__ xprobe,   // d_in[0], dtype probe only
    void* __restrict__ out) {
  __shared__ __align__(16) __hip_bfloat16 Ks[64 * 72];  // [k][d]
  __shared__ __align__(16) __hip_bfloat16 Vt[80 * 68];  // [d][key]; row 64 ones, 65..79 zero
  __shared__ __align__(16) __hip_bfloat16 Ps[64 * 72];  // [q][key] (wave-private strips)

  const int fl = detect_fp32_wave(xprobe);     // no barriers, no LDS
  const int h  = blockIdx.y;
  const int bx = blockIdx.x;
  // XCD swizzle: blocks with equal bx%8 get 8 consecutive tiles -> shared
  // K/V windows in one XCD's L2.
  const int i0 = 64 * ((bx & 7) * 8 + (bx >> 3));
  const int t    = threadIdx.x;
  const int wave = t >> 6, lane = t & 63;
  const int l15 = lane & 15, quad = lane >> 4;
  const float slope2  = exp2f(-0.5f * (float)(h + 1)) * LOG2E;  // m_h*log2(e)
  const float nslope2 = -slope2;                                // bias = nslope2*(i-j)
  const float qscale  = LOG2E / 32.0f;

  // ones/zero rows of Vt (staging only touches rows 0..63)
  for (int idx = t; idx < 16 * 68; idx += 256) {
    int rr = idx / 68, cc = idx - rr * 68;
    ((unsigned short*)Vt)[(64 + rr) * 68 + cc] = (rr == 0) ? 0x3F80 : 0;
  }

  // Q fragments direct to registers: A[m=l15][k=quad*8+j], rows wave*16+l15
  short8 aq[2];
#pragma unroll
  for (int ks2 = 0; ks2 < 2; ++ks2)
    aq[ks2] = *(const short8*)&kqv[(i0 + wave * 16 + l15) * N3 + DM + h * HD +
                                   ks2 * 32 + quad * 8];

  float4v o[5] = {};   // o[dt][r]: row quad*4+r, col dt*16+l15; dt=4 is l-column

  const int jlo  = max(0, i0 - WIN);       // 64-aligned
  const int nblk = (i0 + 64 - jlo) >> 6;   // <= 9

  // ---- staging geometry + prefetch of block 0 ----
  const int krow0 = t >> 3, krow1 = (t >> 3) + 32, kd0 = (t & 7) * 8;
  const int vr0 = (t >> 3) * 2, vd0 = (t & 7) * 8;
  uint4 kregA, kregB, vregA, vregB;
  kregA = *(const uint4*)&kqv[(jlo + krow0) * N3 + h * HD + kd0];
  kregB = *(const uint4*)&kqv[(jlo + krow1) * N3 + h * HD + kd0];
  vregA = *(const uint4*)&kqv[(jlo + vr0) * N3 + 2 * DM + h * HD + vd0];
  vregB = *(const uint4*)&kqv[(jlo + vr0 + 1) * N3 + 2 * DM + h * HD + vd0];

  for (int b = 0; b < nblk; ++b) {
    const int j0 = jlo + b * 64;
    __syncthreads();   // prev iter's K/V readers done before overwrite
    // ---- LDS fill from prefetched registers ----
    *(uint4*)&Ks[krow0 * 72 + kd0] = kregA;
    *(uint4*)&Ks[krow1 * 72 + kd0] = kregB;
    {
      const unsigned short* pa = (const unsigned short*)&vregA;
      const unsigned short* pb = (const unsigned short*)&vregB;
#pragma unroll
      for (int e = 0; e < 8; ++e) {
        unsigned int pack = (unsigned int)pa[e] | ((unsigned int)pb[e] << 16);
        *(unsigned int*)&Vt[(vd0 + e) * 68 + vr0] = pack;
      }
    }
    __syncthreads();   // nothing outstanding here: prefetch not yet issued

    // ---- issue next block's prefetch NOW (covered by compute below) ----
    if (b + 1 < nblk) {
      const int jn = j0 + 64;
      kregA = *(const uint4*)&kqv[(jn + krow0) * N3 + h * HD + kd0];
      kregB = *(const uint4*)&kqv[(jn + krow1) * N3 + h * HD + kd0];
      vregA = *(const uint4*)&kqv[(jn + vr0) * N3 + 2 * DM + h * HD + vd0];
      vregB = *(const uint4*)&kqv[(jn + vr0 + 1) * N3 + 2 * DM + h * HD + vd0];
    }

    // ---- S = Q*K^T : 4 n-tiles x 2 k-steps ----
    float4v sacc[4] = {};
#pragma unroll
    for (int ks2 = 0; ks2 < 2; ++ks2)
#pragma unroll
      for (int nt = 0; nt < 4; ++nt) {
        short8 bk = *(const short8*)&Ks[(nt * 16 + l15) * 72 + ks2 * 32 + quad * 8];
        sacc[nt] = __builtin_amdgcn_mfma_f32_16x16x32_bf16(aq[ks2], bk, sacc[nt], 0, 0, 0);
      }

    // ---- fixed-max softmax: p = exp2(x), masked -> 0 ----
    const int dbase = (i0 + wave * 16 + quad * 4) - (j0 + l15);
    const float s16 = nslope2 * -16.0f;   // bias step per nt
#pragma unroll
    for (int r = 0; r < 4; ++r) {
      float bias = nslope2 * (float)(dbase + r);
      int rel = dbase + r;
#pragma unroll
      for (int nt = 0; nt < 4; ++nt) {
        float x = fmaf(sacc[nt][r], qscale, bias);
        x = ((unsigned)rel <= (unsigned)WIN) ? x : -200.0f;  // exp2(-200)==0
        Ps[(wave * 16 + quad * 4 + r) * 72 + nt * 16 + l15] =
            __float2bfloat16(exp2f(x));
        bias += s16;
        rel -= 16;
      }
    }
    // no barrier: Ps strip is wave-private

    // ---- O += P*V (dt 0..3) ; l += P*1 (dt 4, ones-row of Vt) ----
#pragma unroll
    for (int ks = 0; ks < 64; ks += 32) {
      short8 ap = *(const short8*)&Ps[(wave * 16 + l15) * 72 + ks + quad * 8];
#pragma unroll
      for (int dt = 0; dt < 5; ++dt) {
        const __hip_bfloat16* vp = &Vt[(dt * 16 + l15) * 68 + ks + quad * 8];
        short4v v0 = *(const short4v*)vp;
        short4v v1 = *(const short4v*)(vp + 4);
        short8 bv = __builtin_shufflevector(v0, v1, 0, 1, 2, 3, 4, 5, 6, 7);
        o[dt] = __builtin_amdgcn_mfma_f32_16x16x32_bf16(ap, bv, o[dt], 0, 0, 0);
      }
    }
  }

  // ---- epilogue: l lives in o[4] col 0 (lane l15==0 of each quad group) ----
#pragma unroll
  for (int r = 0; r < 4; ++r) {
    const float l = __shfl(o[4][r], quad * 16, 64);   // broadcast from l15==0 lane
    const float inv_l = 1.0f / l;    // l >= 2^-2: diagonal key j=i always valid
    const int row = i0 + wave * 16 + quad * 4 + r;
#pragma unroll
    for (int dt = 0; dt < 4; ++dt) {
      const int idx = row * DM + h * HD + dt * 16 + l15;
      const float v = o[dt][r] * inv_l;
      if (fl) ((float*)out)[idx] = v;
      else    ((__hip_bfloat16*)out)[idx] = __float2bfloat16(v);
    }
  }
}

// ---------------------------------------------------------------------------
extern "C" void kernel_launch(void* const* d_in, const int* in_sizes, int n_in,
                              void* d_out, int out_size, void* d_ws, size_t ws_size,
                              hipStream_t stream) {
  char* ws = (char*)d_ws;
  __hip_bfloat16* wt  = (__hip_bfloat16*)(ws + 4096);          // 6 MB
  __hip_bfloat16* kqv = (__hip_bfloat16*)(ws + 4096 + 6291456);// 24 MB
  // xb lives in d_out's first 8 MB: dead until attn's epilogue overwrites all
  // of d_out, and gemm_kqv (the only xb reader) completes before attn runs.
  __hip_bfloat16* xb  = (__hip_bfloat16*)d_out;

  hipLaunchKernelGGL(prep, dim3(2048 + 768), dim3(256), 0, stream,
                     d_in[0], d_in[1], xb, wt);
  hipLaunchKernelGGL(gemm_kqv, dim3(24, 32), dim3(256), 0, stream, xb, wt, kqv);
  hipLaunchKernelGGL(attn, dim3(64, 16), dim3(256), 0, stream,
                     kqv, (const unsigned short*)d_in[0], d_out);
}